// Round 2
// baseline (6650.143 us; speedup 1.0000x reference)
//
#include <hip/hip_runtime.h>

// ---------------------------------------------------------------------------
// Autoformer forward, MI355X. Round 2: f32, batch-chunked to fit ws_size.
// B=32, L=512 (enc & dec), D=512, C=21, MARK=4, FF=2048, MA_K=25, top_k=6
// ---------------------------------------------------------------------------

__device__ __forceinline__ float gelu_f(float x){
    return 0.5f * x * (1.0f + erff(x * 0.70710678118654752f));
}

__global__ void zero_k(float* __restrict__ p, long n){
    long i = (long)blockIdx.x * 256 + threadIdx.x;
    if (i < n) p[i] = 0.f;
}

// ------------------------------ GEMM (f32) ---------------------------------
// C = A(MxK)*B + epilogue.  TB=0: B is KxN (ldb). TB=1: B is NxK (ldb).
// EPI: 0 none, 1 v+=R[idx], 2 gelu(v), 3 v+=C[idx] (accumulate in place).
// 128x128 tile, BK=16, 256 threads, 8x8 per thread.
template<int EPI, int TB>
__global__ __launch_bounds__(256)
void gemm_k(const float* __restrict__ A, const float* __restrict__ Bm,
            const float* __restrict__ R, float* __restrict__ C,
            int M, int N, int K, int lda, int ldb, int ldc,
            long sA, long sB, long sC)
{
    __shared__ float As[16][128];
    __shared__ float Bs[16][128];
    const int bz = blockIdx.z;
    A  += (long)bz * sA;
    Bm += (long)bz * sB;
    C  += (long)bz * sC;
    const float* Rp = (EPI == 1) ? (R + (long)bz * sC) : nullptr;
    const int bm = blockIdx.y * 128, bn = blockIdx.x * 128;
    const int tid = threadIdx.x;
    const int tx = tid & 15, ty = tid >> 4;

    float acc[8][8];
#pragma unroll
    for (int i = 0; i < 8; i++)
#pragma unroll
        for (int j = 0; j < 8; j++) acc[i][j] = 0.f;

    const int arow = tid >> 1, akc = (tid & 1) * 8;
    for (int k0 = 0; k0 < K; k0 += 16) {
        const float* ap = A + (long)(bm + arow) * lda + k0 + akc;
        float4 av0 = *(const float4*)ap;
        float4 av1 = *(const float4*)(ap + 4);
        As[akc+0][arow] = av0.x; As[akc+1][arow] = av0.y;
        As[akc+2][arow] = av0.z; As[akc+3][arow] = av0.w;
        As[akc+4][arow] = av1.x; As[akc+5][arow] = av1.y;
        As[akc+6][arow] = av1.z; As[akc+7][arow] = av1.w;
        if (TB == 0) {
            const int bk = tid >> 4, bn0 = (tid & 15) * 8;
            const float* bp = Bm + (long)(k0 + bk) * ldb + bn + bn0;
            float4 bv0 = *(const float4*)bp;
            float4 bv1 = *(const float4*)(bp + 4);
            *(float4*)&Bs[bk][bn0]     = bv0;
            *(float4*)&Bs[bk][bn0 + 4] = bv1;
        } else {
            const int brow = tid >> 1, bkc = (tid & 1) * 8;
            const float* bp = Bm + (long)(bn + brow) * ldb + k0 + bkc;
            float4 bv0 = *(const float4*)bp;
            float4 bv1 = *(const float4*)(bp + 4);
            Bs[bkc+0][brow] = bv0.x; Bs[bkc+1][brow] = bv0.y;
            Bs[bkc+2][brow] = bv0.z; Bs[bkc+3][brow] = bv0.w;
            Bs[bkc+4][brow] = bv1.x; Bs[bkc+5][brow] = bv1.y;
            Bs[bkc+6][brow] = bv1.z; Bs[bkc+7][brow] = bv1.w;
        }
        __syncthreads();
#pragma unroll
        for (int k = 0; k < 16; k++) {
            float4 a0 = *(const float4*)&As[k][ty * 8];
            float4 a1 = *(const float4*)&As[k][ty * 8 + 4];
            float4 b0 = *(const float4*)&Bs[k][tx * 8];
            float4 b1 = *(const float4*)&Bs[k][tx * 8 + 4];
            float aa[8] = {a0.x,a0.y,a0.z,a0.w,a1.x,a1.y,a1.z,a1.w};
            float bb[8] = {b0.x,b0.y,b0.z,b0.w,b1.x,b1.y,b1.z,b1.w};
#pragma unroll
            for (int i = 0; i < 8; i++)
#pragma unroll
                for (int j = 0; j < 8; j++)
                    acc[i][j] = fmaf(aa[i], bb[j], acc[i][j]);
        }
        __syncthreads();
    }
#pragma unroll
    for (int i = 0; i < 8; i++) {
        long crow = (long)(bm + ty * 8 + i) * ldc + bn + tx * 8;
#pragma unroll
        for (int j = 0; j < 8; j++) {
            float v = acc[i][j];
            if (EPI == 1) v += Rp[crow + j];
            if (EPI == 2) v = gelu_f(v);
            if (EPI == 3) v += C[crow + j];
            C[crow + j] = v;
        }
    }
}

// ------------------------- embedding (conv3 + mark + pe) -------------------
// grid (64, 2, Bc), 256 threads. Each block: 8 l's, 256 d's.
__global__ __launch_bounds__(256)
void embed_k(const float* __restrict__ x, const float* __restrict__ mark,
             const float* __restrict__ valW, const float* __restrict__ timeW,
             float* __restrict__ out)
{
    const int lg = blockIdx.x, dh = blockIdx.y, b = blockIdx.z;
    const int tid = threadIdx.x;
    const int dd = dh * 256 + tid;
    const int l0 = lg * 8;
    __shared__ float xs[10][21];
    __shared__ float mk[8][4];
    if (tid < 210) {
        int r = tid / 21, c = tid % 21;
        int ll = (l0 - 1 + r + 512) & 511;           // circular
        xs[r][c] = x[((long)b * 512 + ll) * 21 + c];
    }
    if (tid >= 224 && tid < 256) {
        int t2 = tid - 224, il = t2 >> 2, m = t2 & 3;
        mk[il][m] = mark[((long)b * 512 + l0 + il) * 4 + m];
    }
    __syncthreads();
    float acc[8];
#pragma unroll
    for (int il = 0; il < 8; il++) acc[il] = 0.f;
    for (int t = 0; t < 3; t++)
        for (int c = 0; c < 21; c++) {
            float w = valW[(t * 21 + c) * 512 + dd];
#pragma unroll
            for (int il = 0; il < 8; il++)
                acc[il] = fmaf(xs[il + t][c], w, acc[il]);
        }
    for (int m = 0; m < 4; m++) {
        float w = timeW[m * 512 + dd];
#pragma unroll
        for (int il = 0; il < 8; il++)
            acc[il] = fmaf(mk[il][m], w, acc[il]);
    }
    const float freq = expf((float)(dd & ~1) * (-9.210340371976184f / 512.0f));
#pragma unroll
    for (int il = 0; il < 8; il++) {
        float ang = (float)(l0 + il) * freq;
        float pe = (dd & 1) ? cosf(ang) : sinf(ang);
        out[((long)b * 512 + l0 + il) * 512 + dd] = acc[il] + pe;
    }
}

// ------------------------- series decomp (C=21 and C=512) ------------------
__global__ void decomp21_k(const float* __restrict__ x, float* __restrict__ seas,
                           float* __restrict__ trend, int total)
{
    int i = blockIdx.x * 256 + threadIdx.x;
    if (i >= total) return;
    int c = i % 21, l = (i / 21) % 512, b = i / 10752;
    float s = 0.f;
    for (int j = -12; j <= 12; j++) {
        int ll = l + j; ll = ll < 0 ? 0 : (ll > 511 ? 511 : ll);
        s += x[((long)b * 512 + ll) * 21 + c];
    }
    float t = s * (1.f / 25.f);
    trend[i] = t;
    seas[i] = x[i] - t;
}

template<int TREND>
__global__ __launch_bounds__(256)
void decomp512_k(const float* __restrict__ x, float* __restrict__ out,
                 float* __restrict__ ts)
{
    long i = (long)blockIdx.x * 256 + threadIdx.x;
    int d = (int)(i & 511), l = (int)((i >> 9) & 511), b = (int)(i >> 18);
    const float* xb = x + ((long)b << 18);
    float s = 0.f;
#pragma unroll
    for (int j = -12; j <= 12; j++) {
        int ll = l + j; ll = ll < 0 ? 0 : (ll > 511 ? 511 : ll);
        s += xb[((long)ll << 9) + d];
    }
    float t = s * (1.f / 25.f);
    out[i] = x[i] - t;
    if (TREND) ts[i] += t;
}

// ------------------------- small prep kernels ------------------------------
__global__ void meanseq_k(const float* __restrict__ x, float* __restrict__ xm, int total)
{
    int i = blockIdx.x * 256 + threadIdx.x;
    if (i >= total) return;
    int c = i % 21, b = i / 21;
    float s = 0.f;
    for (int l = 0; l < 512; l++) s += x[((long)b * 512 + l) * 21 + c];
    xm[i] = s * (1.f / 512.f);
}

__global__ void buildinit_k(const float* __restrict__ seas, const float* __restrict__ trend,
                            const float* __restrict__ xm,
                            float* __restrict__ sinit, float* __restrict__ tinit, int total)
{
    int i = blockIdx.x * 256 + threadIdx.x;
    if (i >= total) return;
    int c = i % 21, l = (i / 21) % 512, b = i / 10752;
    if (l < 256) {
        sinit[i] = seas[((long)b * 512 + 256 + l) * 21 + c];
        tinit[i] = trend[((long)b * 512 + 256 + l) * 21 + c];
    } else {
        sinit[i] = 0.f;
        tinit[i] = xm[b * 21 + c];
    }
}

// ------------------------- autocorrelation pieces --------------------------
// mean_corr[b,tau] = (1/512) sum_m S[b][(m+tau)%512][m]
__global__ void diagred_k(const float* __restrict__ S, float* __restrict__ mc)
{
    int tau = blockIdx.x * 256 + threadIdx.x;   // grid (2, Bc)
    int b = blockIdx.y;
    const float* Sb = S + ((long)b << 18);
    float s = 0.f;
    for (int m = 0; m < 512; m++)
        s += Sb[((long)((m + tau) & 511) << 9) + m];
    mc[b * 512 + tau] = s * (1.f / 512.f);
}

// top-6 + softmax, one block per batch. Ties -> lower index (matches lax.top_k).
__global__ __launch_bounds__(256)
void topk_k(const float* __restrict__ mc, int* __restrict__ delays,
            float* __restrict__ wts)
{
    int b = blockIdx.x, tid = threadIdx.x;
    __shared__ float v[512];
    __shared__ float rv[256];
    __shared__ int   ri[256];
    __shared__ float selv[6];
    v[tid] = mc[b * 512 + tid];
    v[tid + 256] = mc[b * 512 + tid + 256];
    __syncthreads();
    for (int p = 0; p < 6; p++) {
        float bv = v[tid]; int bi = tid;
        float v2 = v[tid + 256];
        if (v2 > bv) { bv = v2; bi = tid + 256; }
        rv[tid] = bv; ri[tid] = bi;
        __syncthreads();
        for (int s = 128; s > 0; s >>= 1) {
            if (tid < s) {
                float ov = rv[tid + s]; int oi = ri[tid + s];
                if (ov > rv[tid] || (ov == rv[tid] && oi < ri[tid])) {
                    rv[tid] = ov; ri[tid] = oi;
                }
            }
            __syncthreads();
        }
        if (tid == 0) { selv[p] = rv[0]; delays[b * 6 + p] = ri[0]; v[ri[0]] = -3.4e38f; }
        __syncthreads();
    }
    if (tid == 0) {
        float mx = selv[0];
        for (int p = 1; p < 6; p++) mx = fmaxf(mx, selv[p]);
        float e[6], sum = 0.f;
        for (int p = 0; p < 6; p++) { e[p] = expf(selv[p] - mx); sum += e[p]; }
        for (int p = 0; p < 6; p++) wts[b * 6 + p] = e[p] / sum;
    }
}

// out[b,l,d] = sum_k w[b,k] * V[b,(l+delay[b,k])%512,d]
__global__ __launch_bounds__(256)
void agg_k(const float* __restrict__ V, const int* __restrict__ delays,
           const float* __restrict__ wts, float* __restrict__ out)
{
    long i = (long)blockIdx.x * 256 + threadIdx.x;
    int d = (int)(i & 511), l = (int)((i >> 9) & 511), b = (int)(i >> 18);
    const float* Vb = V + ((long)b << 18);
    float s = 0.f;
#pragma unroll
    for (int k = 0; k < 6; k++) {
        int dl = delays[b * 6 + k];
        float w = wts[b * 6 + k];
        s = fmaf(w, Vb[((long)((l + dl) & 511) << 9) + d], s);
    }
    out[i] = s;
}

// ------------------------- seasonal layernorm ------------------------------
__global__ __launch_bounds__(256)
void ln_k(const float* __restrict__ x, const float* __restrict__ g,
          const float* __restrict__ be, float* __restrict__ out)
{
    int row = blockIdx.x, tid = threadIdx.x;
    const float* xr = x + ((long)row << 9);
    float v0 = xr[tid], v1 = xr[tid + 256];
    __shared__ float rs[256];
    rs[tid] = v0 + v1; __syncthreads();
    for (int s = 128; s > 0; s >>= 1) { if (tid < s) rs[tid] += rs[tid + s]; __syncthreads(); }
    float mu = rs[0] * (1.f / 512.f);
    __syncthreads();
    float d0 = v0 - mu, d1 = v1 - mu;
    rs[tid] = d0 * d0 + d1 * d1; __syncthreads();
    for (int s = 128; s > 0; s >>= 1) { if (tid < s) rs[tid] += rs[tid + s]; __syncthreads(); }
    float rstd = 1.0f / sqrtf(rs[0] * (1.f / 512.f) + 1e-5f);
    out[((long)row << 9) + tid]       = d0 * rstd * g[tid] + be[tid];
    out[((long)row << 9) + tid + 256] = d1 * rstd * g[tid + 256] + be[tid + 256];
}

__global__ void colpart_k(const float* __restrict__ x, float* __restrict__ cp)
{
    int d = blockIdx.x * 256 + threadIdx.x;   // grid (2, 8, Bc)
    int ch = blockIdx.y, b = blockIdx.z;
    const float* xb = x + ((long)b << 18);
    float s = 0.f;
    for (int l = ch * 64; l < ch * 64 + 64; l++) s += xb[((long)l << 9) + d];
    cp[((long)(b * 8 + ch) << 9) + d] = s;
}

__global__ __launch_bounds__(256)
void subcol_k(const float* __restrict__ x, const float* __restrict__ cp,
              float* __restrict__ out)
{
    long i = (long)blockIdx.x * 256 + threadIdx.x;
    int d = (int)(i & 511), b = (int)(i >> 18);
    float m = 0.f;
#pragma unroll
    for (int ch = 0; ch < 8; ch++) m += cp[((long)(b * 8 + ch) << 9) + d];
    out[i] = x[i] - m * (1.f / 512.f);
}

// ------------------------- trend conv + projection -------------------------
__global__ void trendconv_k(const float* __restrict__ ts, const float* __restrict__ W,
                            const float* __restrict__ tinit, float* __restrict__ out, int total)
{
    int i = blockIdx.x * 256 + threadIdx.x;
    if (i >= total) return;
    int c = i % 21, l = (i / 21) % 512, b = i / 10752;
    const float* tb = ts + ((long)b << 18);
    float s = 0.f;
    for (int t = 0; t < 3; t++) {
        int ll = (l + t - 1 + 512) & 511;            // circular
        const float* row = tb + ((long)ll << 9);
        const float* wr = W + (long)t * 512 * 21 + c;
        for (int d = 0; d < 512; d++)
            s = fmaf(row[d], wr[d * 21], s);
    }
    out[i] = tinit[i] + s;
}

__global__ void proj_k(const float* __restrict__ x, const float* __restrict__ pw,
                       const float* __restrict__ pb, const float* __restrict__ trend,
                       float* __restrict__ out, int total)
{
    int i = blockIdx.x * 256 + threadIdx.x;
    if (i >= total) return;
    int c = i % 21, l = (i / 21) % 256 + 256, b = i / 5376;
    const float* xr = x + ((long)(b * 512 + l) << 9);
    float s = 0.f;
    for (int d = 0; d < 512; d++) s = fmaf(xr[d], pw[d * 21 + c], s);
    out[i] = s + pb[c] + trend[((long)b * 512 + l) * 21 + c];
}

// ---------------------------------------------------------------------------
static void g_launch(int epi, int tb,
                     const float* A, const float* B, const float* R, float* C,
                     int M, int N, int K, int lda, int ldb, int ldc,
                     int batch, long sA, long sB, long sC, hipStream_t st)
{
    dim3 g(N / 128, M / 128, batch), blk(256);
    if (tb == 1) { gemm_k<0,1><<<g,blk,0,st>>>(A,B,R,C,M,N,K,lda,ldb,ldc,sA,sB,sC); return; }
    switch (epi) {
    case 0: gemm_k<0,0><<<g,blk,0,st>>>(A,B,R,C,M,N,K,lda,ldb,ldc,sA,sB,sC); break;
    case 1: gemm_k<1,0><<<g,blk,0,st>>>(A,B,R,C,M,N,K,lda,ldb,ldc,sA,sB,sC); break;
    case 2: gemm_k<2,0><<<g,blk,0,st>>>(A,B,R,C,M,N,K,lda,ldb,ldc,sA,sB,sC); break;
    default:gemm_k<3,0><<<g,blk,0,st>>>(A,B,R,C,M,N,K,lda,ldb,ldc,sA,sB,sC); break;
    }
}

extern "C" void kernel_launch(void* const* d_in, const int* in_sizes, int n_in,
                              void* d_out, int out_size, void* d_ws, size_t ws_size,
                              hipStream_t stream)
{
    const float* x_enc    = (const float*)d_in[0];
    const float* xm_enc   = (const float*)d_in[1];
    const float* xm_dec   = (const float*)d_in[3];
    const float* enc_valW = (const float*)d_in[4];
    const float* enc_timeW= (const float*)d_in[5];
    const float* enc_Wq   = (const float*)d_in[6];
    const float* enc_Wk   = (const float*)d_in[7];
    const float* enc_Wv   = (const float*)d_in[8];
    const float* enc_Wo   = (const float*)d_in[9];
    const float* enc_W1   = (const float*)d_in[10];
    const float* enc_W2   = (const float*)d_in[11];
    const float* enc_g    = (const float*)d_in[12];
    const float* enc_b    = (const float*)d_in[13];
    const float* dec_valW = (const float*)d_in[14];
    const float* dec_timeW= (const float*)d_in[15];
    const float* sWq = (const float*)d_in[16];
    const float* sWk = (const float*)d_in[17];
    const float* sWv = (const float*)d_in[18];
    const float* sWo = (const float*)d_in[19];
    const float* cWq = (const float*)d_in[20];
    const float* cWk = (const float*)d_in[21];
    const float* cWv = (const float*)d_in[22];
    const float* cWo = (const float*)d_in[23];
    const float* dW1 = (const float*)d_in[24];
    const float* dW2 = (const float*)d_in[25];
    const float* dtW = (const float*)d_in[26];
    const float* dec_g = (const float*)d_in[27];
    const float* dec_b = (const float*)d_in[28];
    const float* projW = (const float*)d_in[29];
    const float* projB = (const float*)d_in[30];

    // ---- pick batch-chunk size from ws_size (constant -> deterministic) ----
    int Bc = 32;
    for (;;) {
        size_t nbc = (size_t)Bc * 262144;
        size_t small = (size_t)Bc * 10752 * 5 + (size_t)Bc * (21 + 512 + 4096 + 12) + 256;
        if ((7 * nbc + small) * 4 <= ws_size || Bc == 1) break;
        Bc >>= 1;
    }
    const long NBc = (long)Bc * 262144;
    float* ws  = (float*)d_ws;
    float* Abuf = ws;
    float* Bbuf = ws + NBc;
    float* Qb  = ws + 2 * NBc;   // FFN hidden chunk aliases Qb
    float* Kb  = ws + 3 * NBc;
    float* Vb  = ws + 4 * NBc;
    float* ENC = ws + 5 * NBc;
    float* TS  = ws + 6 * NBc;
    float* sm  = ws + 7 * NBc;
    float* seas_s  = sm;
    float* trend_t = seas_s  + (long)Bc * 10752;
    float* sinit   = trend_t + (long)Bc * 10752;
    float* tinit   = sinit   + (long)Bc * 10752;
    float* tfinal  = tinit   + (long)Bc * 10752;
    float* xmean   = tfinal  + (long)Bc * 10752;
    float* mc      = xmean   + (long)Bc * 21;
    float* cp      = mc      + (long)Bc * 512;
    float* wts     = cp      + (long)Bc * 4096;
    int*   delays  = (int*)(wts + (long)Bc * 6);

    const long sQ = 262144;          // per-batch stride 512*512
    const int M = Bc * 512;          // row count for row-space gemms
    const int t21 = Bc * 10752;      // Bc*512*21
    const int gNB = (int)(NBc / 256);

    // attention helper: Q from X, K/V from KVs; scratch for S/agg; out += into X
    auto attn = [&](float* X, float* scr, const float* KVs,
                    const float* Wq, const float* Wk, const float* Wv, const float* Wo) {
        g_launch(0,0, X,   Wq, nullptr, Qb, M, 512, 512, 512, 512, 512, 1, 0,0,0, stream);
        g_launch(0,0, KVs, Wk, nullptr, Kb, M, 512, 512, 512, 512, 512, 1, 0,0,0, stream);
        g_launch(0,0, KVs, Wv, nullptr, Vb, M, 512, 512, 512, 512, 512, 1, 0,0,0, stream);
        g_launch(0,1, Qb, Kb, nullptr, scr, 512, 512, 512, 512, 512, 512, Bc, sQ, sQ, sQ, stream);
        diagred_k<<<dim3(2,Bc), 256, 0, stream>>>(scr, mc);
        topk_k   <<<Bc, 256, 0, stream>>>(mc, delays, wts);
        agg_k    <<<gNB, 256, 0, stream>>>(Vb, delays, wts, scr);
        g_launch(1,0, scr, Wo, X, X, M, 512, 512, 512, 512, 512, 1, 0,0,0, stream);
    };
    // FFN: Xout = gelu(X @ W1) @ W2 + X   (FF chunked by 512, hidden in Qb)
    auto ffn = [&](const float* X, float* Xout, const float* W1, const float* W2) {
        for (int cc = 0; cc < 4; cc++) {
            g_launch(2,0, X, W1 + cc * 512, nullptr, Qb, M, 512, 512, 512, 2048, 512, 1, 0,0,0, stream);
            if (cc == 0)
                g_launch(1,0, Qb, W2 + (long)cc * 512 * 512, X, Xout, M, 512, 512, 512, 512, 512, 1, 0,0,0, stream);
            else
                g_launch(3,0, Qb, W2 + (long)cc * 512 * 512, nullptr, Xout, M, 512, 512, 512, 512, 512, 1, 0,0,0, stream);
        }
    };

    for (int c0 = 0; c0 < 32; c0 += Bc) {
        const float* xe  = x_enc  + (long)c0 * 10752;
        const float* mke = xm_enc + (long)c0 * 2048;
        const float* mkd = xm_dec + (long)c0 * 2048;
        float* outp = (float*)d_out + (long)c0 * 5376;

        // ---------------- stage 0: inits ----------------
        meanseq_k  <<<(Bc*21 + 255)/256, 256, 0, stream>>>(xe, xmean, Bc*21);
        decomp21_k <<<t21/256, 256, 0, stream>>>(xe, seas_s, trend_t, t21);
        buildinit_k<<<t21/256, 256, 0, stream>>>(seas_s, trend_t, xmean, sinit, tinit, t21);

        // ---------------- encoder ----------------
        embed_k<<<dim3(64,2,Bc), 256, 0, stream>>>(xe, mke, enc_valW, enc_timeW, Abuf);
        float* X = Abuf; float* O = Bbuf;
        for (int layer = 0; layer < 2; layer++) {
            attn(X, O, X, enc_Wq + (long)layer*sQ, enc_Wk + (long)layer*sQ,
                 enc_Wv + (long)layer*sQ, enc_Wo + (long)layer*sQ);
            decomp512_k<0><<<gNB, 256, 0, stream>>>(X, O, nullptr);
            { float* t = X; X = O; O = t; }
            ffn(X, O, enc_W1 + (long)layer*512*2048, enc_W2 + (long)layer*2048*512);
            decomp512_k<0><<<gNB, 256, 0, stream>>>(O, X, nullptr);
        }
        // X holds encoder pre-norm output; O is scratch
        ln_k     <<<Bc*512, 256, 0, stream>>>(X, enc_g, enc_b, O);
        colpart_k<<<dim3(2,8,Bc), 256, 0, stream>>>(O, cp);
        subcol_k <<<gNB, 256, 0, stream>>>(O, cp, ENC);

        // ---------------- decoder ----------------
        embed_k<<<dim3(64,2,Bc), 256, 0, stream>>>(sinit, mkd, dec_valW, dec_timeW, Abuf);
        zero_k <<<gNB, 256, 0, stream>>>(TS, NBc);

        attn(Abuf, Bbuf, Abuf, sWq, sWk, sWv, sWo);                 // self
        decomp512_k<1><<<gNB, 256, 0, stream>>>(Abuf, Bbuf, TS);    // X -> Bbuf
        attn(Bbuf, Abuf, ENC, cWq, cWk, cWv, cWo);                  // cross
        decomp512_k<1><<<gNB, 256, 0, stream>>>(Bbuf, Abuf, TS);    // X -> Abuf
        ffn(Abuf, Bbuf, dW1, dW2);
        decomp512_k<1><<<gNB, 256, 0, stream>>>(Bbuf, Abuf, TS);    // X -> Abuf

        trendconv_k<<<t21/256, 256, 0, stream>>>(TS, dtW, tinit, tfinal, t21);
        ln_k     <<<Bc*512, 256, 0, stream>>>(Abuf, dec_g, dec_b, Bbuf);
        colpart_k<<<dim3(2,8,Bc), 256, 0, stream>>>(Bbuf, cp);
        subcol_k <<<gNB, 256, 0, stream>>>(Bbuf, cp, Bbuf);         // in-place
        proj_k   <<<Bc*21, 256, 0, stream>>>(Bbuf, projW, projB, tfinal, outp, Bc*5376);
    }
}